// Round 1
// baseline (433.461 us; speedup 1.0000x reference)
//
#include <hip/hip_runtime.h>

// Problem constants
#define NPTS  32768
#define KNB   16
#define CH    128
#define INNER 512
#define EPS   1e-5f

// Workspace layout (float offsets)
#define WS_M    0        // M = Wv@Wo   : 128*128 = 16384 floats
#define WS_COEF 16384    // a[128], b[128] : 256 floats
#define WS_P    32768    // per-block partials: 1024 blocks * 256 = 262144 floats
#define WS_P2   294912   // stage-2 partials: 256 * 256 = 65536 floats
// total 360448 floats = ~1.41 MB of ws

// ---------------------------------------------------------------------------
// Kernel 1: M = Wv @ Wo   (128x512 @ 512x128 -> 128x128)
// One thread per output element. Wv row load is wave-uniform (broadcast),
// Wo row load is coalesced across lanes.
// ---------------------------------------------------------------------------
__global__ __launch_bounds__(256) void k_wvwo(const float* __restrict__ Wv,
                                              const float* __restrict__ Wo,
                                              float* __restrict__ M) {
    int id = blockIdx.x * 256 + threadIdx.x;   // 0..16383
    int c  = id >> 7;
    int cp = id & 127;
    const float* wvr = Wv + c * INNER;
    float acc = 0.f;
#pragma unroll 8
    for (int i = 0; i < INNER; ++i)
        acc = fmaf(wvr[i], Wo[i * CH + cp], acc);
    M[c * CH + cp] = acc;
}

// ---------------------------------------------------------------------------
// Kernel 2 (main): per block of 32 points:
//   phase 1: hs[p][c] = sum_k h[n,k,c]   (streams 256 MB total, coalesced f4)
//   phase 2: y[p][c'] = hs[p][:] @ M[:,c']  (M rows from global, L1/L2-hot)
//   epilogue: y -> d_out, per-channel sum/sumsq partials -> ws
// ---------------------------------------------------------------------------
__global__ __launch_bounds__(256) void k_main(const float* __restrict__ h,
                                              const float* __restrict__ Mg,
                                              float* __restrict__ y,
                                              float* __restrict__ partials) {
    __shared__ float4 hs4[32 * 32];      // hs[32 pts][128 ch] as float4
    __shared__ float  red[4][2][128];    // cross-wave stat reduce

    const int t  = threadIdx.x;
    const int n0 = blockIdx.x * 32;
    const float4* __restrict__ h4 = (const float4*)h;

    // ---- phase 1: k-sum ----
    // pair index pi -> point p = pi>>5, channel-quad c4 = pi&31
#pragma unroll 2
    for (int j = 0; j < 4; ++j) {
        int pi = t + 256 * j;
        int p  = pi >> 5;
        int c4 = pi & 31;
        size_t base = (size_t)(n0 + p) * (KNB * 32) + c4;  // float4 index
        float4 a = h4[base];
#pragma unroll
        for (int k = 1; k < KNB; ++k) {
            float4 v = h4[base + (size_t)k * 32];
            a.x += v.x; a.y += v.y; a.z += v.z; a.w += v.w;
        }
        hs4[p * 32 + c4] = a;
    }
    __syncthreads();

    // ---- phase 2: GEMV  y = hs @ M ----
    const int w  = t >> 6;     // wave 0..3
    const int l  = t & 63;     // lane
    const int p0 = w * 8;      // 8 points per wave
    float acc0[8] = {0,0,0,0,0,0,0,0};   // channel l
    float acc1[8] = {0,0,0,0,0,0,0,0};   // channel l+64

    for (int cc = 0; cc < 32; ++cc) {
        const int c = 4 * cc;
        // coalesced 256B row-segments of M; L1-resident after first touch
        float m00 = Mg[(c + 0) * CH + l];
        float m01 = Mg[(c + 1) * CH + l];
        float m02 = Mg[(c + 2) * CH + l];
        float m03 = Mg[(c + 3) * CH + l];
        float m10 = Mg[(c + 0) * CH + 64 + l];
        float m11 = Mg[(c + 1) * CH + 64 + l];
        float m12 = Mg[(c + 2) * CH + 64 + l];
        float m13 = Mg[(c + 3) * CH + 64 + l];
#pragma unroll
        for (int p = 0; p < 8; ++p) {
            float4 hv = hs4[(p0 + p) * 32 + cc];   // LDS broadcast (free)
            acc0[p] = fmaf(hv.x, m00, acc0[p]);
            acc0[p] = fmaf(hv.y, m01, acc0[p]);
            acc0[p] = fmaf(hv.z, m02, acc0[p]);
            acc0[p] = fmaf(hv.w, m03, acc0[p]);
            acc1[p] = fmaf(hv.x, m10, acc1[p]);
            acc1[p] = fmaf(hv.y, m11, acc1[p]);
            acc1[p] = fmaf(hv.z, m12, acc1[p]);
            acc1[p] = fmaf(hv.w, m13, acc1[p]);
        }
    }

    // ---- epilogue: write y, accumulate stats ----
    float s0 = 0.f, s1 = 0.f, q0 = 0.f, q1 = 0.f;
#pragma unroll
    for (int p = 0; p < 8; ++p) {
        size_t row = (size_t)(n0 + p0 + p) * CH;
        y[row + l]      = acc0[p];
        y[row + 64 + l] = acc1[p];
        s0 += acc0[p];  q0 = fmaf(acc0[p], acc0[p], q0);
        s1 += acc1[p];  q1 = fmaf(acc1[p], acc1[p], q1);
    }
    red[w][0][l]      = s0;
    red[w][0][64 + l] = s1;
    red[w][1][l]      = q0;
    red[w][1][64 + l] = q1;
    __syncthreads();

    // 256 threads: (stat s, channel c) = (t>>7, t&127)
    {
        int s = t >> 7, c = t & 127;
        float v = red[0][s][c] + red[1][s][c] + red[2][s][c] + red[3][s][c];
        partials[(size_t)blockIdx.x * 256 + t] = v;   // coalesced
    }
}

// ---------------------------------------------------------------------------
// Kernel 3a: compress 1024 partial rows -> 256 rows
// ---------------------------------------------------------------------------
__global__ __launch_bounds__(256) void k_red1(const float* __restrict__ P,
                                              float* __restrict__ P2) {
    int t  = threadIdx.x;
    int bb = blockIdx.x;
    const float* p0 = P + (size_t)(4 * bb) * 256;
    float v = p0[t] + p0[256 + t] + p0[512 + t] + p0[768 + t];
    P2[(size_t)bb * 256 + t] = v;
}

// ---------------------------------------------------------------------------
// Kernel 3b: final reduce + BN coefficient computation
//   coef[c]     = gamma[c] * rsqrt(var+eps)
//   coef[128+c] = beta[c] - mu * coef[c]
// ---------------------------------------------------------------------------
__global__ __launch_bounds__(1024) void k_red2(const float* __restrict__ P2,
                                               const float* __restrict__ gamma,
                                               const float* __restrict__ beta,
                                               float* __restrict__ coef) {
    __shared__ float red[4][256];
    int t = threadIdx.x;
    int q = t >> 8, e = t & 255;
    float s = 0.f;
    for (int r = q * 64; r < q * 64 + 64; ++r)
        s += P2[(size_t)r * 256 + e];
    red[q][e] = s;
    __syncthreads();
    if (t < 256) {
        float tot = red[0][t] + red[1][t] + red[2][t] + red[3][t];
        red[0][t] = tot;
    }
    __syncthreads();
    if (t < 128) {
        float S  = red[0][t];
        float Q  = red[0][128 + t];
        float mu = S * (1.f / NPTS);
        float var = Q * (1.f / NPTS) - mu * mu;   // biased variance
        float rs = rsqrtf(var + EPS);
        float a  = gamma[t] * rs;
        coef[t]       = a;
        coef[128 + t] = beta[t] - mu * a;
    }
}

// ---------------------------------------------------------------------------
// Kernel 4: in-place normalize + ReLU on d_out
// ---------------------------------------------------------------------------
__global__ __launch_bounds__(256) void k_norm(float* __restrict__ y,
                                              const float* __restrict__ coef) {
    int gid = blockIdx.x * 256 + threadIdx.x;       // 262144 threads
    float4* y4 = (float4*)y;
    const float4* c4 = (const float4*)coef;
    int lc = gid & 31;                              // same channel-quad every iter
    float4 a = c4[lc];
    float4 b = c4[32 + lc];
#pragma unroll
    for (int i = 0; i < 4; ++i) {
        size_t idx = (size_t)gid + (size_t)i * 262144;
        float4 v = y4[idx];
        v.x = fmaxf(0.f, fmaf(v.x, a.x, b.x));
        v.y = fmaxf(0.f, fmaf(v.y, a.y, b.y));
        v.z = fmaxf(0.f, fmaf(v.z, a.z, b.z));
        v.w = fmaxf(0.f, fmaf(v.w, a.w, b.w));
        y4[idx] = v;
    }
}

// ---------------------------------------------------------------------------
extern "C" void kernel_launch(void* const* d_in, const int* in_sizes, int n_in,
                              void* d_out, int out_size, void* d_ws, size_t ws_size,
                              hipStream_t stream) {
    // inputs: h, x, Wq, Wk, Wv, Wo, bo, gamma, beta
    const float* h     = (const float*)d_in[0];
    const float* Wv    = (const float*)d_in[4];
    const float* Wo    = (const float*)d_in[5];
    const float* gamma = (const float*)d_in[7];
    const float* beta  = (const float*)d_in[8];
    // x, Wq, Wk are dead (softmax over singleton dim == 1); bo cancels in BN.

    float* out  = (float*)d_out;
    float* ws   = (float*)d_ws;
    float* M    = ws + WS_M;
    float* coef = ws + WS_COEF;
    float* P    = ws + WS_P;
    float* P2   = ws + WS_P2;

    k_wvwo<<<64,   256, 0, stream>>>(Wv, Wo, M);
    k_main<<<1024, 256, 0, stream>>>(h, M, out, P);
    k_red1<<<256,  256, 0, stream>>>(P, P2);
    k_red2<<<1,   1024, 0, stream>>>(P2, gamma, beta, coef);
    k_norm<<<1024, 256, 0, stream>>>(out, coef);
}